// Round 6
// baseline (2201.451 us; speedup 1.0000x reference)
//
#include <hip/hip_runtime.h>
#include <math.h>
#include <stdint.h>

#define HID 256
#define NGRAPH 64
typedef unsigned short ushort_t;

typedef __attribute__((ext_vector_type(8))) short short8;
typedef __attribute__((ext_vector_type(4))) float f32x4;

// exact fp32 -> bf16 hi/lo split (RNE both)
__device__ __forceinline__ void split2(float v, ushort_t& h, ushort_t& l) {
  unsigned u = __float_as_uint(v);
  unsigned hr = u + 0x7FFFu + ((u >> 16) & 1u);
  h = (ushort_t)(hr >> 16);
  float hf = __uint_as_float(((unsigned)h) << 16);
  float r = v - hf;
  unsigned u2 = __float_as_uint(r);
  unsigned lr = u2 + 0x7FFFu + ((u2 >> 16) & 1u);
  l = (ushort_t)(lr >> 16);
}

#define GLDS(g, l) \
  __builtin_amdgcn_global_load_lds((const __attribute__((address_space(1))) void*)(g), \
                                   (__attribute__((address_space(3))) void*)(l), 16, 0, 0)

// ---------------- MFMA split-bf16 GEMM, fused N=512 ----------------
// A: [Mpad][Kpad] bf16 hi/lo. B: [512][Kpad] bf16 hi/lo (Wl^T rows 0-255, Wr^T 256-511).
// C: [M][512] fp32 = A*B^T (3-term split: hh + hl + lh)
// Block: 128(M) x 256(N), 512 threads (8 waves of 64x64). Grid (2, mblocks).
// LDS chunks XOR-swizzled: chunk (r, c) -> slot c ^ ((r>>1)&3) => 2-way banks on read (free).
__global__ __launch_bounds__(512) void mfma_gemm512_kernel(
    const ushort_t* __restrict__ Ah, const ushort_t* __restrict__ Al,
    const ushort_t* __restrict__ Bh, const ushort_t* __restrict__ Bl,
    float* __restrict__ C, int Mrows, int Kpad) {
  __shared__ ushort_t lAh[128 * 32];
  __shared__ ushort_t lAl[128 * 32];
  __shared__ ushort_t lBh[256 * 32];
  __shared__ ushort_t lBl[256 * 32];
  const int tid = threadIdx.x;
  const int m0 = blockIdx.y * 128;
  const int n0 = blockIdx.x * 256;
  const int w = tid >> 6, lane = tid & 63;
  const int wm = (w >> 2) * 64, wn = (w & 3) * 64;
  const int col = lane & 15, quad = lane >> 4;

  // staging source indices (slot = tid / tid+512; global chunk xor-permuted)
  const int rA = tid >> 2;
  const int cA = (tid & 3) ^ ((rA >> 1) & 3);
  const int rB1 = rA + 128;  // second B slot: same xor since (rB1>>1)&3 == (rA>>1)&3 ^ 0 (128>>1=64, &3=0)

  f32x4 acc[4][4];
#pragma unroll
  for (int i = 0; i < 4; ++i)
#pragma unroll
    for (int j = 0; j < 4; ++j) acc[i][j] = (f32x4)(0.f);

  for (int kt = 0; kt < Kpad; kt += 32) {
    {
      const size_t goA = (size_t)(m0 + rA) * Kpad + kt + cA * 8;
      GLDS(Ah + goA, &lAh[tid * 8]);
      GLDS(Al + goA, &lAl[tid * 8]);
      const size_t goB0 = (size_t)(n0 + rA) * Kpad + kt + cA * 8;
      GLDS(Bh + goB0, &lBh[tid * 8]);
      GLDS(Bl + goB0, &lBl[tid * 8]);
      const size_t goB1 = (size_t)(n0 + rB1) * Kpad + kt + cA * 8;
      GLDS(Bh + goB1, &lBh[(tid + 512) * 8]);
      GLDS(Bl + goB1, &lBl[(tid + 512) * 8]);
    }
    __syncthreads();
    short8 ah[4], al[4], bh[4], bl[4];
#pragma unroll
    for (int i = 0; i < 4; ++i) {
      const int ar = wm + i * 16 + col;
      const int sA = ar * 4 + (quad ^ ((ar >> 1) & 3));
      ah[i] = *(const short8*)&lAh[sA * 8];
      al[i] = *(const short8*)&lAl[sA * 8];
      const int br = wn + i * 16 + col;
      const int sB = br * 4 + (quad ^ ((br >> 1) & 3));
      bh[i] = *(const short8*)&lBh[sB * 8];
      bl[i] = *(const short8*)&lBl[sB * 8];
    }
    __syncthreads();
#pragma unroll
    for (int i = 0; i < 4; ++i)
#pragma unroll
      for (int j = 0; j < 4; ++j) {
        acc[i][j] = __builtin_amdgcn_mfma_f32_16x16x32_bf16(ah[i], bh[j], acc[i][j], 0, 0, 0);
        acc[i][j] = __builtin_amdgcn_mfma_f32_16x16x32_bf16(ah[i], bl[j], acc[i][j], 0, 0, 0);
        acc[i][j] = __builtin_amdgcn_mfma_f32_16x16x32_bf16(al[i], bh[j], acc[i][j], 0, 0, 0);
      }
  }
#pragma unroll
  for (int i = 0; i < 4; ++i) {
    const int r0 = m0 + wm + i * 16 + quad * 4;
#pragma unroll
    for (int j = 0; j < 4; ++j) {
      const int cc = n0 + wn + j * 16 + col;
#pragma unroll
      for (int r = 0; r < 4; ++r)
        if (r0 + r < Mrows) C[(size_t)(r0 + r) * 512 + cc] = acc[i][j][r];
    }
  }
}

// ---------------- attention GEMM (N=128) with fused tanh-dot scorer ----------------
// computes t = h@Wa1 per 128x128 tile, then s[m] = sum_c tanh(t[m][c]+ba1[c])*Wa2[c] + ba2
__global__ __launch_bounds__(256) void mfma_att_kernel(
    const ushort_t* __restrict__ Ah, const ushort_t* __restrict__ Al,
    const ushort_t* __restrict__ Bh, const ushort_t* __restrict__ Bl,
    const float* __restrict__ ba1, const float* __restrict__ Wa2,
    const float* __restrict__ ba2, float* __restrict__ S, int Mrows, int Kpad) {
  __shared__ ushort_t lAh[128 * 32];
  __shared__ ushort_t lAl[128 * 32];
  __shared__ ushort_t lBh[128 * 32];
  __shared__ ushort_t lBl[128 * 32];
  __shared__ float sat[128][2];
  const int tid = threadIdx.x;
  const int m0 = blockIdx.y * 128;
  const int w = tid >> 6, lane = tid & 63;
  const int wm = (w >> 1) * 64, wn = (w & 1) * 64;
  const int col = lane & 15, quad = lane >> 4;

  f32x4 acc[4][4];
#pragma unroll
  for (int i = 0; i < 4; ++i)
#pragma unroll
    for (int j = 0; j < 4; ++j) acc[i][j] = (f32x4)(0.f);

  for (int kt = 0; kt < Kpad; kt += 32) {
#pragma unroll
    for (int j = 0; j < 2; ++j) {
      const int ch = tid + j * 256;
      const int r = ch >> 2, c = ch & 3;
      const size_t goA = (size_t)(m0 + r) * Kpad + kt + c * 8;
      const size_t goB = (size_t)r * Kpad + kt + c * 8;
      GLDS(Ah + goA, &lAh[ch * 8]);
      GLDS(Al + goA, &lAl[ch * 8]);
      GLDS(Bh + goB, &lBh[ch * 8]);
      GLDS(Bl + goB, &lBl[ch * 8]);
    }
    __syncthreads();
    short8 ah[4], al[4], bh[4], bl[4];
#pragma unroll
    for (int i = 0; i < 4; ++i) {
      const int ar = wm + i * 16 + col;
      ah[i] = *(const short8*)&lAh[ar * 32 + quad * 8];
      al[i] = *(const short8*)&lAl[ar * 32 + quad * 8];
      const int br = wn + i * 16 + col;
      bh[i] = *(const short8*)&lBh[br * 32 + quad * 8];
      bl[i] = *(const short8*)&lBl[br * 32 + quad * 8];
    }
    __syncthreads();
#pragma unroll
    for (int i = 0; i < 4; ++i)
#pragma unroll
      for (int j = 0; j < 4; ++j) {
        acc[i][j] = __builtin_amdgcn_mfma_f32_16x16x32_bf16(ah[i], bh[j], acc[i][j], 0, 0, 0);
        acc[i][j] = __builtin_amdgcn_mfma_f32_16x16x32_bf16(ah[i], bl[j], acc[i][j], 0, 0, 0);
        acc[i][j] = __builtin_amdgcn_mfma_f32_16x16x32_bf16(al[i], bh[j], acc[i][j], 0, 0, 0);
      }
  }
  // epilogue: per-row tanh-dot
  float part[4][4];
#pragma unroll
  for (int i = 0; i < 4; ++i)
#pragma unroll
    for (int r = 0; r < 4; ++r) part[i][r] = 0.f;
#pragma unroll
  for (int j = 0; j < 4; ++j) {
    const int cc = wn + j * 16 + col;
    const float a1 = ba1[cc];
    const float w2 = Wa2[cc];
#pragma unroll
    for (int i = 0; i < 4; ++i)
#pragma unroll
      for (int r = 0; r < 4; ++r)
        part[i][r] += tanhf(acc[i][j][r] + a1) * w2;
  }
#pragma unroll
  for (int mask = 1; mask < 16; mask <<= 1)
#pragma unroll
    for (int i = 0; i < 4; ++i)
#pragma unroll
      for (int r = 0; r < 4; ++r) part[i][r] += __shfl_xor(part[i][r], mask, 64);
  if (col == 0) {
#pragma unroll
    for (int i = 0; i < 4; ++i)
#pragma unroll
      for (int r = 0; r < 4; ++r) sat[wm + i * 16 + quad * 4 + r][wn >> 6] = part[i][r];
  }
  __syncthreads();
  if (tid < 128) {
    const int gm = m0 + tid;
    if (gm < Mrows) S[gm] = sat[tid][0] + sat[tid][1] + ba2[0];
  }
}

// ---------------- conversions ----------------
__global__ __launch_bounds__(256) void convert_x_kernel(
    const float* __restrict__ x, int nrows,
    ushort_t* __restrict__ xh, ushort_t* __restrict__ xl, int K, int Kpad) {
  const int perRow = Kpad / 4;
  const int t = blockIdx.x * blockDim.x + threadIdx.x;
  if (t >= nrows * perRow) return;
  const int r = t / perRow, k0 = (t % perRow) * 4;
  const float* xr = x + (size_t)r * K;
  ushort_t h[4], l[4];
#pragma unroll
  for (int i = 0; i < 4; ++i) {
    const float v = (k0 + i < K) ? xr[k0 + i] : 0.f;
    split2(v, h[i], l[i]);
  }
  const size_t o = (size_t)r * Kpad + k0;
  *(ushort4*)(xh + o) = make_ushort4(h[0], h[1], h[2], h[3]);
  *(ushort4*)(xl + o) = make_ushort4(l[0], l[1], l[2], l[3]);
}

// fused transpose+split: rows n<256 from W1[k][n], n>=256 from W2[k][n-256]
__global__ void convert_wt_kernel(const float* __restrict__ W1, const float* __restrict__ W2,
                                  ushort_t* __restrict__ wth, ushort_t* __restrict__ wtl,
                                  int K, int Kpad, int ntot, int ld) {
  const int t = blockIdx.x * blockDim.x + threadIdx.x;
  if (t >= ntot * Kpad) return;
  const int n = t / Kpad, k = t % Kpad;
  float v = 0.f;
  if (k < K) v = (n < 256) ? W1[(size_t)k * ld + n] : W2[(size_t)k * ld + (n - 256)];
  ushort_t h, l;
  split2(v, h, l);
  wth[t] = h;
  wtl[t] = l;
}

// ---------------- CSR build ----------------
__global__ void deg_count_kernel(const int* __restrict__ dst, int* __restrict__ degi, int nE) {
  int e = blockIdx.x * blockDim.x + threadIdx.x;
  if (e < nE) atomicAdd(&degi[dst[e]], 1);
}

__global__ __launch_bounds__(1024) void scan_kernel(const int* __restrict__ degi,
                                                    int* __restrict__ rowptr, int M) {
  __shared__ int part[1024];
  const int t = threadIdx.x;
  const int chunk = (M + 1023) / 1024;
  const int b0 = min(t * chunk, M);
  const int b1 = min(b0 + chunk, M);
  int s = 0;
  for (int i = b0; i < b1; ++i) s += degi[i];
  part[t] = s;
  __syncthreads();
  for (int off = 1; off < 1024; off <<= 1) {
    int v = (t >= off) ? part[t - off] : 0;
    __syncthreads();
    part[t] += v;
    __syncthreads();
  }
  int ex = (t == 0) ? 0 : part[t - 1];
  for (int i = b0; i < b1; ++i) {
    rowptr[i] = ex;
    ex += degi[i];
  }
  if (t == 1023) rowptr[M] = part[1023];
}

__global__ void fill_kernel(const int* __restrict__ src, const int* __restrict__ dst,
                            int* __restrict__ fill, const int* __restrict__ rowptr,
                            int* __restrict__ csr_src, int nE) {
  int e = blockIdx.x * blockDim.x + threadIdx.x;
  if (e >= nE) return;
  const int d = dst[e];
  const int pos = rowptr[d] + atomicAdd(&fill[d], 1);
  csr_src[pos] = src[e];
}

// ---------------- fused gather-mean + bias + hr + BN stats ----------------
// gbuf: [M][512] (cols 0-255 = hl, 256-511 = hr)
#define GNB 64
__global__ __launch_bounds__(256) void gather_combine_kernel(
    const float* __restrict__ gbuf,
    const int* __restrict__ rowptr, const int* __restrict__ csr_src,
    const float* __restrict__ bl, float* preBN,
    float* __restrict__ bsum, float* __restrict__ bsumsq, int M) {
  __shared__ float lsum[4][HID];
  __shared__ float lsq[4][HID];
  const int w = threadIdx.x >> 6;
  const int lane = threadIdx.x & 63;
  const float4 blv = ((const float4*)bl)[lane];
  float4 s = make_float4(0.f, 0.f, 0.f, 0.f);
  float4 q = make_float4(0.f, 0.f, 0.f, 0.f);
  const int base = blockIdx.x * GNB;
  for (int it = 0; it < GNB / 4; ++it) {
    const int n = base + it * 4 + w;
    if (n < M) {
      const int e0 = rowptr[n], e1 = rowptr[n + 1];
      float4 acc = make_float4(0.f, 0.f, 0.f, 0.f);
      for (int e = e0; e < e1; ++e) {
        const int sn = csr_src[e];
        const float4 v = ((const float4*)(gbuf + (size_t)sn * 512))[lane];
        acc.x += v.x; acc.y += v.y; acc.z += v.z; acc.w += v.w;
      }
      const float rd = 1.0f / fmaxf((float)(e1 - e0), 1.0f);
      const float4 hv = ((const float4*)(gbuf + (size_t)n * 512 + 256))[lane];
      float4 o;
      o.x = fmaf(acc.x, rd, blv.x + hv.x);
      o.y = fmaf(acc.y, rd, blv.y + hv.y);
      o.z = fmaf(acc.z, rd, blv.z + hv.z);
      o.w = fmaf(acc.w, rd, blv.w + hv.w);
      ((float4*)(preBN + (size_t)n * HID))[lane] = o;
      s.x += o.x; s.y += o.y; s.z += o.z; s.w += o.w;
      q.x = fmaf(o.x, o.x, q.x); q.y = fmaf(o.y, o.y, q.y);
      q.z = fmaf(o.z, o.z, q.z); q.w = fmaf(o.w, o.w, q.w);
    }
  }
  *(float4*)&lsum[w][lane * 4] = s;
  *(float4*)&lsq[w][lane * 4] = q;
  __syncthreads();
  const int c = threadIdx.x;
  const float ts = lsum[0][c] + lsum[1][c] + lsum[2][c] + lsum[3][c];
  const float tq = lsq[0][c] + lsq[1][c] + lsq[2][c] + lsq[3][c];
  atomicAdd(&bsum[c], ts);
  atomicAdd(&bsumsq[c], tq);
}

// BN(scale/shift recomputed per block) + ReLU -> bf16 split (+ optional fp32)
__global__ __launch_bounds__(256) void bn_apply_relu_convert_kernel(
    const float* __restrict__ preBN, const float* __restrict__ bsum,
    const float* __restrict__ bsumsq, const float* __restrict__ g, const float* __restrict__ b,
    ushort_t* __restrict__ hh, ushort_t* __restrict__ hl, float* __restrict__ hout,
    int M, int n4) {
  __shared__ float s_sc[HID], s_sh[HID];
  {
    const int c = threadIdx.x;
    const float inv = 1.0f / (float)M;
    const float mean = bsum[c] * inv;
    const float var = bsumsq[c] * inv - mean * mean;
    const float sc = g[c] * rsqrtf(var + 1e-5f);
    s_sc[c] = sc;
    s_sh[c] = b[c] - mean * sc;
  }
  __syncthreads();
  const int i = blockIdx.x * blockDim.x + threadIdx.x;
  if (i >= n4) return;
  const int c0 = (i & (HID / 4 - 1)) * 4;
  const float4 v = ((const float4*)preBN)[i];
  float o[4];
  o[0] = fmaxf(fmaf(v.x, s_sc[c0 + 0], s_sh[c0 + 0]), 0.f);
  o[1] = fmaxf(fmaf(v.y, s_sc[c0 + 1], s_sh[c0 + 1]), 0.f);
  o[2] = fmaxf(fmaf(v.z, s_sc[c0 + 2], s_sh[c0 + 2]), 0.f);
  o[3] = fmaxf(fmaf(v.w, s_sc[c0 + 3], s_sh[c0 + 3]), 0.f);
  ushort_t h[4], l[4];
#pragma unroll
  for (int k = 0; k < 4; ++k) split2(o[k], h[k], l[k]);
  ((ushort4*)hh)[i] = make_ushort4(h[0], h[1], h[2], h[3]);
  ((ushort4*)hl)[i] = make_ushort4(l[0], l[1], l[2], l[3]);
  if (hout) ((float4*)hout)[i] = make_float4(o[0], o[1], o[2], o[3]);
}

// ---------------- softmax over graphs ----------------
__device__ __forceinline__ unsigned fflip(float f) {
  unsigned u = __float_as_uint(f);
  return (u & 0x80000000u) ? ~u : (u | 0x80000000u);
}
__device__ __forceinline__ float funflip(unsigned u) {
  return __uint_as_float((u & 0x80000000u) ? (u ^ 0x80000000u) : ~u);
}

__global__ void seg_max_kernel(const float* __restrict__ s, const int* __restrict__ batch,
                               unsigned* __restrict__ gmax, int M) {
  __shared__ unsigned lmax[NGRAPH];
  if (threadIdx.x < NGRAPH) lmax[threadIdx.x] = 0u;
  __syncthreads();
  for (int i = blockIdx.x * blockDim.x + threadIdx.x; i < M; i += gridDim.x * blockDim.x)
    atomicMax(&lmax[batch[i]], fflip(s[i]));
  __syncthreads();
  if (threadIdx.x < NGRAPH && lmax[threadIdx.x] != 0u) atomicMax(&gmax[threadIdx.x], lmax[threadIdx.x]);
}

__global__ void seg_expsum_kernel(const float* __restrict__ s, const int* __restrict__ batch,
                                  const unsigned* __restrict__ gmax, float* __restrict__ e,
                                  float* __restrict__ denom, int M) {
  __shared__ float ld[NGRAPH];
  if (threadIdx.x < NGRAPH) ld[threadIdx.x] = 0.f;
  __syncthreads();
  for (int i = blockIdx.x * blockDim.x + threadIdx.x; i < M; i += gridDim.x * blockDim.x) {
    const int b = batch[i];
    const float v = expf(s[i] - funflip(gmax[b]));
    e[i] = v;
    atomicAdd(&ld[b], v);
  }
  __syncthreads();
  if (threadIdx.x < NGRAPH && ld[threadIdx.x] != 0.f) atomicAdd(&denom[threadIdx.x], ld[threadIdx.x]);
}

#define PNB 16
__global__ __launch_bounds__(256) void pool_kernel(
    const float* __restrict__ h, const float* __restrict__ e, const float* __restrict__ denom,
    const int* __restrict__ batch, float* __restrict__ pooled, int M) {
  const int wid = (blockIdx.x * blockDim.x + threadIdx.x) >> 6;
  const int lane = threadIdx.x & 63;
  const int n0 = wid * PNB;
  if (n0 >= M) return;
  const int n1 = min(n0 + PNB, M);
  float4 acc = make_float4(0.f, 0.f, 0.f, 0.f);
  int cur = batch[n0];
  for (int n = n0; n < n1; ++n) {
    const int b = batch[n];
    if (b != cur) {
      float* o = pooled + (size_t)cur * HID + lane * 4;
      atomicAdd(o + 0, acc.x); atomicAdd(o + 1, acc.y);
      atomicAdd(o + 2, acc.z); atomicAdd(o + 3, acc.w);
      acc = make_float4(0.f, 0.f, 0.f, 0.f);
      cur = b;
    }
    const float w = e[n] / denom[b];
    const float4 v = ((const float4*)(h + (size_t)n * HID))[lane];
    acc.x = fmaf(v.x, w, acc.x); acc.y = fmaf(v.y, w, acc.y);
    acc.z = fmaf(v.z, w, acc.z); acc.w = fmaf(v.w, w, acc.w);
  }
  float* o = pooled + (size_t)cur * HID + lane * 4;
  atomicAdd(o + 0, acc.x); atomicAdd(o + 1, acc.y);
  atomicAdd(o + 2, acc.z); atomicAdd(o + 3, acc.w);
}

__global__ __launch_bounds__(128) void classifier_kernel(
    const float* __restrict__ pooled, const float* __restrict__ Wc1, const float* __restrict__ bc1,
    const float* __restrict__ Wc2, const float* __restrict__ bc2, float* __restrict__ out) {
  __shared__ float red[128];
  const int g = blockIdx.x;
  const int j = threadIdx.x;
  float acc = bc1[j];
  const float* p = pooled + (size_t)g * HID;
  for (int c = 0; c < HID; ++c) acc = fmaf(p[c], Wc1[c * 128 + j], acc);
  red[j] = fmaxf(acc, 0.f) * Wc2[j];
  __syncthreads();
  for (int off = 64; off > 0; off >>= 1) {
    if (j < off) red[j] += red[j + off];
    __syncthreads();
  }
  if (j == 0) out[g] = red[0] + bc2[0];
}

extern "C" void kernel_launch(void* const* d_in, const int* in_sizes, int n_in,
                              void* d_out, int out_size, void* d_ws, size_t ws_size,
                              hipStream_t stream) {
  const float* x = (const float*)d_in[0];
  const int* edge = (const int*)d_in[1];
  const int* batch = (const int*)d_in[2];
  const int M = in_sizes[2];
  const int nE = in_sizes[1] / 2;
  const int IN_DIM = in_sizes[0] / M;  // 771
  const int* src = edge;
  const int* dst = edge + nE;

  const int Mpad = ((M + 127) / 128) * 128;
  const int KP0 = ((IN_DIM + 31) / 32) * 32;  // 800
  const int mblocks = (M + 127) / 128;

  float* ws = (float*)d_ws;
  float* gbuf = ws;                                    // [M][512]
  float* pbuf = gbuf + (size_t)M * 512;                // [M][256]
  float* h32 = pbuf + (size_t)M * HID;                 // [M][256]
  float* ssc = h32 + (size_t)M * HID;                  // M
  float* ew = ssc + M;                                 // M
  float* bsumA = ew + M;                               // 3 layers x (256 sum + 256 sq)
  unsigned* gmax = (unsigned*)(bsumA + 6 * HID);       // 64
  float* denom = (float*)(gmax + NGRAPH);              // 64
  float* pooled = denom + NGRAPH;                      // 64*256
  int* degi = (int*)(pooled + (size_t)NGRAPH * HID);   // M
  int* filla = degi + M;                               // M
  int* rowptr = filla + M;                             // M+1
  int* csr_src = rowptr + M + 1;                       // nE

  ushort_t* wp = (ushort_t*)(((uintptr_t)(csr_src + nE) + 15) & ~(uintptr_t)15);
  ushort_t* w0h = wp;                 ushort_t* w0l = w0h + (size_t)512 * KP0;
  ushort_t* w1h = w0l + (size_t)512 * KP0;  ushort_t* w1l = w1h + (size_t)512 * HID;
  ushort_t* w2h = w1l + (size_t)512 * HID;  ushort_t* w2l = w2h + (size_t)512 * HID;
  ushort_t* wah = w2l + (size_t)512 * HID;  ushort_t* wal = wah + (size_t)128 * HID;
  ushort_t* cvh = (ushort_t*)(((uintptr_t)(wal + (size_t)128 * HID) + 15) & ~(uintptr_t)15);
  ushort_t* cvl = cvh + (size_t)Mpad * KP0;

  // ---- CSR build ----
  hipMemsetAsync(degi, 0, (size_t)(2 * M) * sizeof(int), stream);
  deg_count_kernel<<<(nE + 255) / 256, 256, 0, stream>>>(dst, degi, nE);
  scan_kernel<<<1, 1024, 0, stream>>>(degi, rowptr, M);
  fill_kernel<<<(nE + 255) / 256, 256, 0, stream>>>(src, dst, filla, rowptr, csr_src, nE);
  // one memset for all small accumulators: bsumA(1536) + gmax(64) + denom(64) + pooled(16384)
  hipMemsetAsync(bsumA, 0, (size_t)(6 * HID + 2 * NGRAPH + NGRAPH * HID) * 4, stream);

  // ---- weight transpose + split (fused Wl||Wr per layer) ----
  {
    const int nt0 = 512 * KP0;
    convert_wt_kernel<<<(nt0 + 255) / 256, 256, 0, stream>>>(
        (const float*)d_in[3], (const float*)d_in[5], w0h, w0l, IN_DIM, KP0, 512, HID);
    const int nt1 = 512 * HID;
    convert_wt_kernel<<<(nt1 + 255) / 256, 256, 0, stream>>>(
        (const float*)d_in[8], (const float*)d_in[10], w1h, w1l, HID, HID, 512, HID);
    convert_wt_kernel<<<(nt1 + 255) / 256, 256, 0, stream>>>(
        (const float*)d_in[13], (const float*)d_in[15], w2h, w2l, HID, HID, 512, HID);
    convert_wt_kernel<<<(128 * HID + 255) / 256, 256, 0, stream>>>(
        (const float*)d_in[18], nullptr, wah, wal, HID, HID, 128, 128);
  }

  // layer-0 input split
  {
    const int nt = M * (KP0 / 4);
    convert_x_kernel<<<(nt + 255) / 256, 256, 0, stream>>>(x, M, cvh, cvl, IN_DIM, KP0);
  }

  const int n4 = (int)((size_t)M * HID / 4);
  const ushort_t* WH[3] = {w0h, w1h, w2h};
  const ushort_t* WL[3] = {w0l, w1l, w2l};
  for (int l = 0; l < 3; ++l) {
    const int KP = (l == 0) ? KP0 : HID;
    const float* bl = (const float*)d_in[3 + l * 5 + 1];
    const float* gg = (const float*)d_in[3 + l * 5 + 3];
    const float* bb = (const float*)d_in[3 + l * 5 + 4];
    float* bsum = bsumA + l * 512;
    float* bsumsq = bsum + HID;

    dim3 g(2, mblocks);
    mfma_gemm512_kernel<<<g, 512, 0, stream>>>(cvh, cvl, WH[l], WL[l], gbuf, M, KP);
    gather_combine_kernel<<<(M + GNB - 1) / GNB, 256, 0, stream>>>(
        gbuf, rowptr, csr_src, bl, pbuf, bsum, bsumsq, M);
    // overwrite cvh/cvl with next layer's split ([Mpad][256] fits in [Mpad][800] region)
    bn_apply_relu_convert_kernel<<<(n4 + 255) / 256, 256, 0, stream>>>(
        pbuf, bsum, bsumsq, gg, bb, cvh, cvl, (l == 2) ? h32 : nullptr, M, n4);
  }

  // attention scores (GEMM + fused tanh-dot epilogue)
  {
    dim3 g(1, mblocks);
    mfma_att_kernel<<<g, 256, 0, stream>>>(
        cvh, cvl, wah, wal, (const float*)d_in[19], (const float*)d_in[20],
        (const float*)d_in[21], ssc, M, HID);
  }
  seg_max_kernel<<<512, 256, 0, stream>>>(ssc, batch, gmax, M);
  seg_expsum_kernel<<<512, 256, 0, stream>>>(ssc, batch, gmax, ew, denom, M);
  {
    const int nwaves = (M + PNB - 1) / PNB;
    pool_kernel<<<(nwaves * 64 + 255) / 256, 256, 0, stream>>>(h32, ew, denom, batch, pooled, M);
  }
  classifier_kernel<<<NGRAPH, 128, 0, stream>>>(
      pooled, (const float*)d_in[22], (const float*)d_in[23],
      (const float*)d_in[24], (const float*)d_in[25], (float*)d_out);
}